// Round 15
// baseline (300.718 us; speedup 1.0000x reference)
//
#include <hip/hip_runtime.h>

using f32x4  = __attribute__((ext_vector_type(4))) float;
using frag16 = __attribute__((ext_vector_type(8))) short;
using s16x4  = __attribute__((ext_vector_type(4))) short;
using s16x8  = __attribute__((ext_vector_type(8))) short;
using u32x4  = __attribute__((ext_vector_type(4))) unsigned;

#define DI __device__ __forceinline__

constexpr int HID  = 2048;
constexpr int NH   = 16;
constexpr int HD   = 128;
constexpr int TT   = 4096;   // total tokens
constexpr int SEQ  = 2048;
constexpr int NQKV = 3 * HID; // 6144
constexpr float SCL = 0.08838834764831845f * 1.4426950408889634f; // scale*log2e

DI short f2bf(float f) {
  unsigned u = __builtin_bit_cast(unsigned, f);
  unsigned r = (u + 0x7fffu + ((u >> 16) & 1u)) >> 16;
  return (short)r;
}
DI float bf2f(short s) {
  unsigned u = ((unsigned)(unsigned short)s) << 16;
  return __builtin_bit_cast(float, u);
}
DI unsigned cvtpk(float lo, float hi) {
  unsigned r;
  asm("v_cvt_pk_bf16_f32 %0, %1, %2" : "=v"(r) : "v"(lo), "v"(hi));
  return r;
}

// ---------------- merged prep: hidden conv + wqkv^T + wo^T (one launch) -----
struct alignas(8) S4h { short a, b, c, d; };

__global__ void prep(const float* __restrict__ hidden, short* __restrict__ Abf,
                     const float* __restrict__ wqkv, short* __restrict__ Wqkvt,
                     const float* __restrict__ wo, short* __restrict__ Wot) {
  __shared__ float t[64][65];
  const int bid = blockIdx.x;
  const int tid = threadIdx.x;
  if (bid < 8192) {                      // f32 -> bf16 convert of hidden
    int gid = bid * 256 + tid;
    float4 v = ((const float4*)hidden)[gid];
    S4h o{f2bf(v.x), f2bf(v.y), f2bf(v.z), f2bf(v.w)};
    ((S4h*)Abf)[gid] = o;
    return;
  }
  const float* in;
  short* out;
  int ldin, R, bx, by;
  if (bid < 8192 + 3072) {               // wqkv (2048 x 6144) -> (6144 x 2048)
    int idx = bid - 8192;
    in = wqkv; out = Wqkvt; ldin = NQKV; R = HID;
    bx = idx % 96; by = idx / 96;
  } else {                               // wo (2048 x 2048) -> (2048 x 2048)
    int idx = bid - 8192 - 3072;
    in = wo; out = Wot; ldin = HID; R = HID;
    bx = idx % 32; by = idx / 32;
  }
#pragma unroll
  for (int i = 0; i < 4; i++) {
    int idx = i * 256 + tid;
    int r = idx >> 4, c4 = idx & 15;
    size_t gi = (size_t)(by * 64 + r) * ldin + bx * 64 + c4 * 4;
    float4 v = *(const float4*)(in + gi);
    t[r][c4 * 4] = v.x; t[r][c4 * 4 + 1] = v.y;
    t[r][c4 * 4 + 2] = v.z; t[r][c4 * 4 + 3] = v.w;
  }
  __syncthreads();
#pragma unroll
  for (int i = 0; i < 4; i++) {
    int idx = i * 256 + tid;
    int r = idx >> 4, c4 = idx & 15;
    s16x4 o;
#pragma unroll
    for (int j = 0; j < 4; j++) o[j] = f2bf(t[c4 * 4 + j][r]);
    *(s16x4*)(out + (size_t)(bx * 64 + r) * R + by * 64 + c4 * 4) = o;
  }
}

// ---------------- post: Vt transpose (token bit-perm) + kc/vc cache scatter --
__global__ void post(const short* __restrict__ Kb, const short* __restrict__ Vrow,
                     short* __restrict__ Vt, const int* __restrict__ slots,
                     float* __restrict__ kc, float* __restrict__ vc) {
  __shared__ float t[64][65];
  const int bid = blockIdx.x;
  const int tid = threadIdx.x;
  if (bid < 2048) {
    int bx = bid & 31, by = bid >> 5;    // bx: HID/64, by: TT/64
#pragma unroll
    for (int i = 0; i < 4; i++) {
      int idx = i * 256 + tid;
      int r = idx >> 4, c4 = idx & 15;
      size_t gi = (size_t)(by * 64 + r) * HID + bx * 64 + c4 * 4;
      s16x4 v = *(const s16x4*)(Vrow + gi);
#pragma unroll
      for (int j = 0; j < 4; j++) t[r][c4 * 4 + j] = bf2f(v[j]);
    }
    __syncthreads();
#pragma unroll
    for (int i = 0; i < 4; i++) {
      int idx = i * 256 + tid;
      int r = idx >> 4, c4 = idx & 15;
      s16x4 o;
#pragma unroll
      for (int j = 0; j < 4; j++) {
        int c = c4 * 4 + j;
        int cs = (c >> 5) * 32 + ((c >> 2) & 1) * 16 + ((c >> 3) & 3) * 4 + (c & 3);
        o[j] = f2bf(t[cs][r]);
      }
      *(s16x4*)(Vt + (size_t)(bx * 64 + r) * TT + by * 64 + c4 * 4) = o;
    }
    return;
  }
  const int tok = bid - 2048;            // 0..4095
  const int slot = slots[tok];
  const short* kr = Kb + (size_t)tok * HID;
  const short* vr = Vrow + (size_t)tok * HID;
  float* kco = kc + (size_t)slot * HID;
  float* vco = vc + (size_t)slot * HID;
  const int i = tid * 8;
  s16x8 k8 = *(const s16x8*)(kr + i);
  s16x8 v8 = *(const s16x8*)(vr + i);
  *(float4*)(kco + i)     = {bf2f(k8[0]), bf2f(k8[1]), bf2f(k8[2]), bf2f(k8[3])};
  *(float4*)(kco + i + 4) = {bf2f(k8[4]), bf2f(k8[5]), bf2f(k8[6]), bf2f(k8[7])};
  *(float4*)(vco + i)     = {bf2f(v8[0]), bf2f(v8[1]), bf2f(v8[2]), bf2f(v8[3])};
  *(float4*)(vco + i + 4) = {bf2f(v8[4]), bf2f(v8[5]), bf2f(v8[6]), bf2f(v8[7])};
}

#define GLDS(src, dst)                                                     \
  __builtin_amdgcn_global_load_lds(                                        \
      (const __attribute__((address_space(1))) void*)(src),                \
      (__attribute__((address_space(3))) void*)(dst), 16, 0, 0)

// ---------------- bf16 MFMA GEMM, B transposed (N x K), 128x128 tile ----------
template <int EPI>
__global__ __launch_bounds__(256, 2) void gemm_bt(
    const short* __restrict__ A, const short* __restrict__ Bt,
    const float* __restrict__ bias, float* __restrict__ Cout,
    const float* __restrict__ cs, const float* __restrict__ sn,
    short* __restrict__ Qb, short* __restrict__ Kb, short* __restrict__ Vrow,
    int M, int N, int K) {
  __shared__ alignas(16) short Al[128 * 64];
  __shared__ alignas(16) short Bl[128 * 64];
  const int tid = threadIdx.x;
  const int wid = tid >> 6, lane = tid & 63;
  const int wr = wid >> 1, wc = wid & 1;
  const int l15 = lane & 15, lg = lane >> 4;
  const int gx = gridDim.x;
  const int id = blockIdx.y * gx + blockIdx.x;
  const int nwg = gx * gridDim.y;
  const int swz = (id & 7) * (nwg >> 3) + (id >> 3);
  const int row0 = (swz / gx) * 128, col0 = (swz % gx) * 128;
  const int lr8 = lane >> 3, l7 = lane & 7;

  f32x4 acc[4][4];
#pragma unroll
  for (int i = 0; i < 4; i++)
#pragma unroll
    for (int j = 0; j < 4; j++) acc[i][j] = {0.f, 0.f, 0.f, 0.f};

  for (int kt = 0; kt < K; kt += 64) {
#pragma unroll
    for (int c = 0; c < 4; c++) {
      int chunk = c * 4 + wid;             // 0..15 (1KB chunks)
      int r = chunk * 8 + lr8;             // LDS row 0..127
      int ke = (l7 * 8) ^ ((r & 7) * 8);   // element offset within 64-wide row
      GLDS(A + (size_t)(row0 + r) * K + kt + ke, Al + chunk * 512);
      GLDS(Bt + (size_t)(col0 + r) * K + kt + ke, Bl + chunk * 512);
    }
    __syncthreads();
#pragma unroll
    for (int kk = 0; kk < 2; kk++) {
      frag16 af[4], bfv[4];
#pragma unroll
      for (int ai = 0; ai < 4; ai++) {
        int r = wr * 64 + ai * 16 + l15;
        int k0 = kk * 32 + lg * 8;
        af[ai] = *(const frag16*)(Al + r * 64 + (k0 ^ ((r & 7) * 8)));
      }
#pragma unroll
      for (int bj = 0; bj < 4; bj++) {
        int r = wc * 16 + (bj & 1) * 32 + ((bj >> 1) << 6) + l15;
        int k0 = kk * 32 + lg * 8;
        bfv[bj] = *(const frag16*)(Bl + r * 64 + (k0 ^ ((r & 7) * 8)));
      }
#pragma unroll
      for (int ai = 0; ai < 4; ai++)
#pragma unroll
        for (int bj = 0; bj < 4; bj++)
          acc[ai][bj] = __builtin_amdgcn_mfma_f32_16x16x32_bf16(
              af[ai], bfv[bj], acc[ai][bj], 0, 0, 0);
    }
    __syncthreads();
  }

  if (EPI == 0) {
#pragma unroll
    for (int ai = 0; ai < 4; ai++) {
#pragma unroll
      for (int bj = 0; bj < 4; bj++) {
        int row = row0 + wr * 64 + ai * 16 + lg * 4;
        int col = col0 + wc * 16 + (bj & 1) * 32 + ((bj >> 1) << 6) + l15;
#pragma unroll
        for (int r = 0; r < 4; r++)
          Cout[(size_t)(row + r) * N + col] = acc[ai][bj][r];
      }
    }
  } else {
    const int sec = col0 >> 11;            // 0=Q 1=K 2=V (uniform per block)
    const int h = (col0 & 2047) >> 7;
#pragma unroll
    for (int ai = 0; ai < 4; ai++) {
#pragma unroll
      for (int bj = 0; bj < 2; bj++) {
        const int d1 = wc * 16 + bj * 32 + l15;   // 0..63
        const float b1 = bias[col0 + d1];
        const float b2 = bias[col0 + d1 + 64];
        const int base = h * 128 + d1;
#pragma unroll
        for (int r = 0; r < 4; r++) {
          const int tok = row0 + wr * 64 + ai * 16 + lg * 4 + r;
          float v1 = acc[ai][bj][r] + b1;
          float v2 = acc[ai][bj + 2][r] + b2;
          if (sec == 0) {
            float c = cs[tok * 64 + d1], s = sn[tok * 64 + d1];
            Qb[(size_t)tok * HID + base]      = f2bf((v1 * c - v2 * s) * SCL);
            Qb[(size_t)tok * HID + base + 64] = f2bf((v2 * c + v1 * s) * SCL);
          } else if (sec == 1) {
            float c = cs[tok * 64 + d1], s = sn[tok * 64 + d1];
            Kb[(size_t)tok * HID + base]      = f2bf(v1 * c - v2 * s);
            Kb[(size_t)tok * HID + base + 64] = f2bf(v2 * c + v1 * s);
          } else {
            Vrow[(size_t)tok * HID + base]      = f2bf(v1);
            Vrow[(size_t)tok * HID + base + 64] = f2bf(v2);
          }
        }
      }
    }
  }
}

// ---------------- causal flash attention v10: KVBLK=32, 4 blocks/CU ----------
// One 64-row strip per block (4 waves x 16 rows), 1024 blocks heavy-first
// banded (per-CU proc-sums balance). LDS 32 KB -> 4 blocks/CU = 4 waves/SIMD
// (2x latency hiding vs v6). Register-direct P (one frag), swapped QK^T,
// defer-max, double-buffered staging.
__global__ __launch_bounds__(256, 4) void flash_attn10(
    const short* __restrict__ Qb, const short* __restrict__ Kb,
    const short* __restrict__ Vt, short* __restrict__ attn) {
  __shared__ alignas(16) short Klds[2][32 * 128];   // 8 KB each
  __shared__ alignas(16) short Vlds[2][128 * 32];   // 8 KB each

  const int tid = threadIdx.x;
  const int w = tid >> 6, lane = tid & 63;
  const int l15 = lane & 15, lg = lane >> 4;
  const int bid = blockIdx.x;
  const int s = 31 - (bid >> 5);           // heavy strips dispatched first
  const int bh = bid & 31;
  const int b = bh >> 4, h = bh & 15;

  frag16 ones;
#pragma unroll
  for (int q = 0; q < 8; q++) ones[q] = (short)0x3F80;

  // stage one 32-token K/V tile (8 KB + 8 KB); 4 GLDS per thread
  auto stage = [&](int kv0, int buf) {
#pragma unroll
    for (int ci = 0; ci < 2; ci++) {
      int e = ci * 256 + w * 64 + lane;    // 0..511 (16B slots)
      int krow = e >> 4;
      int kss = (e & 15) ^ (krow & 15);
      GLDS(Kb + (size_t)(b * SEQ + kv0 + krow) * HID + h * HD + kss * 8,
           Klds[buf] + (ci * 256 + w * 64) * 8);
      int vd = e >> 2;
      int vss = (e & 3) ^ (vd & 3);
      GLDS(Vt + (size_t)(h * HD + vd) * TT + b * SEQ + kv0 + vss * 8,
           Vlds[buf] + (ci * 256 + w * 64) * 8);
    }
  };

  const int qrow0 = s * 64 + w * 16;
  const int nt = 2 * s + 2;                // 32-token tiles covering the strip

  frag16 qf[4];
  {
    const short* qp = Qb + (size_t)(b * SEQ + qrow0 + l15) * HID + h * HD + lg * 8;
#pragma unroll
    for (int ds = 0; ds < 4; ds++) qf[ds] = *(const frag16*)(qp + ds * 32);
  }
  f32x4 o[8];
#pragma unroll
  for (int q = 0; q < 8; q++) o[q] = {0.f, 0.f, 0.f, 0.f};
  f32x4 la = {0.f, 0.f, 0.f, 0.f};
  float mr = -1e30f;                       // per-lane, q = qrow0 + l15

  stage(0, 0);
  __syncthreads();

  int cur = 0;
  for (int t = 0; t < nt; t++) {
    const int kv0 = t * 32;
    if (t + 1 < nt) stage(kv0 + 32, cur ^ 1);
    if (kv0 <= qrow0 + 15) {               // wave-uniform skip
      const short* Kl = &Klds[cur][0];
      const short* Vl = &Vlds[cur][0];
      f32x4 sa[2];
      sa[0] = {0.f, 0.f, 0.f, 0.f};
      sa[1] = {0.f, 0.f, 0.f, 0.f};
      __builtin_amdgcn_s_setprio(1);
#pragma unroll
      for (int ds = 0; ds < 4; ds++) {
        int phys = (ds * 4 + lg) ^ l15;
#pragma unroll
        for (int f = 0; f < 2; f++) {
          frag16 kf = *(const frag16*)(Kl + (f * 16 + l15) * 128 + phys * 8);
          sa[f] = __builtin_amdgcn_mfma_f32_16x16x32_bf16(kf, qf[ds], sa[f], 0, 0, 0);
        }
      }
      __builtin_amdgcn_s_setprio(0);
      if (kv0 + 31 > qrow0) {              // single diagonal tile per wave
        int ql = qrow0 + l15 - kv0;
#pragma unroll
        for (int f = 0; f < 2; f++)
#pragma unroll
          for (int r = 0; r < 4; r++)
            if (f * 16 + lg * 4 + r > ql) sa[f][r] = -1e30f;
      }
      float pm = fmaxf(
          fmaxf(fmaxf(sa[0][0], sa[0][1]), fmaxf(sa[0][2], sa[0][3])),
          fmaxf(fmaxf(sa[1][0], sa[1][1]), fmaxf(sa[1][2], sa[1][3])));
      pm = fmaxf(pm, __shfl_xor(pm, 16));
      pm = fmaxf(pm, __shfl_xor(pm, 32));
      if (__any(pm > mr + 8.f)) {
        float mn = fmaxf(mr, pm);
        float frl = exp2f(mr - mn);
        mr = mn;
        float fr4[4];
#pragma unroll
        for (int r = 0; r < 4; r++)
          fr4[r] = __shfl(frl, lg * 16 + lg * 4 + r);
#pragma unroll
        for (int r = 0; r < 4; r++) {
          la[r] *= fr4[r];
#pragma unroll
          for (int q = 0; q < 8; q++) o[q][r] *= fr4[r];
        }
      }
      float pe[2][4];
#pragma unroll
      for (int f = 0; f < 2; f++)
#pragma unroll
        for (int r = 0; r < 4; r++) pe[f][r] = exp2f(sa[f][r] - mr);
      u32x4 w0;
      w0[0] = cvtpk(pe[0][0], pe[0][1]); w0[1] = cvtpk(pe[0][2], pe[0][3]);
      w0[2] = cvtpk(pe[1][0], pe[1][1]); w0[3] = cvtpk(pe[1][2], pe[1][3]);
      frag16 pf0 = __builtin_bit_cast(frag16, w0);
      __builtin_amdgcn_s_setprio(1);
      la = __builtin_amdgcn_mfma_f32_16x16x32_bf16(pf0, ones, la, 0, 0, 0);
#pragma unroll
      for (int q = 0; q < 8; q++) {
        int d = q * 16 + l15;
        int phys = lg ^ (d & 3);
        frag16 vf = *(const frag16*)(Vl + d * 32 + phys * 8);
        o[q] = __builtin_amdgcn_mfma_f32_16x16x32_bf16(pf0, vf, o[q], 0, 0, 0);
      }
      __builtin_amdgcn_s_setprio(0);
    }
    __syncthreads();
    cur ^= 1;
  }

  float inv[4];
#pragma unroll
  for (int r = 0; r < 4; r++) inv[r] = 1.f / la[r];
  short* op = attn + (size_t)(b * SEQ + qrow0 + lg * 4) * HID + h * HD + l15;
#pragma unroll
  for (int q = 0; q < 8; q++)
#pragma unroll
    for (int r = 0; r < 4; r++)
      op[(size_t)r * HID + q * 16] = f2bf(o[q][r] * inv[r]);
}

// ---------------- launcher ----------------
extern "C" void kernel_launch(void* const* d_in, const int* in_sizes, int n_in,
                              void* d_out, int out_size, void* d_ws, size_t ws_size,
                              hipStream_t stream) {
  const float* hidden = (const float*)d_in[0];
  const float* cosb   = (const float*)d_in[1];
  const float* sinb   = (const float*)d_in[2];
  const float* wqkv   = (const float*)d_in[3];
  const float* bqkv   = (const float*)d_in[4];
  const float* wo     = (const float*)d_in[5];
  const int*   slots  = (const int*)d_in[9];

  float* out = (float*)d_out;
  float* kc  = out + (size_t)TT * HID;
  float* vc  = kc + (size_t)TT * HID;

  short* ws    = (short*)d_ws;
  short* Abf   = ws;                       // 8,388,608 shorts (reused as attnb)
  short* Wqkvt = Abf + 8388608;            // 12,582,912
  short* Wot   = Wqkvt + 12582912;         // 4,194,304
  short* Qb    = Wot + 4194304;            // 8,388,608
  short* Kb    = Qb + 8388608;             // 8,388,608
  short* Vrow  = Kb + 8388608;             // 8,388,608
  short* Vt    = Vrow + 8388608;           // 8,388,608
  short* attnb = Abf;                      // reuse (A dead after GEMM1)

  prep<<<8192 + 3072 + 1024, 256, 0, stream>>>(hidden, Abf, wqkv, Wqkvt, wo, Wot);
  gemm_bt<1><<<dim3(48, 32), 256, 0, stream>>>(
      Abf, Wqkvt, bqkv, nullptr, cosb, sinb, Qb, Kb, Vrow, TT, NQKV, HID);
  post<<<2048 + 4096, 256, 0, stream>>>(Kb, Vrow, Vt, slots, kc, vc);
  flash_attn10<<<1024, 256, 0, stream>>>(Qb, Kb, Vt, attnb);
  gemm_bt<0><<<dim3(16, 32), 256, 0, stream>>>(
      attnb, Wot, nullptr, out, nullptr, nullptr, nullptr, nullptr, nullptr,
      TT, HID, HID);
}

// Round 16
// 284.094 us; speedup vs baseline: 1.0585x; 1.0585x over previous
//
#include <hip/hip_runtime.h>

using f32x4  = __attribute__((ext_vector_type(4))) float;
using frag16 = __attribute__((ext_vector_type(8))) short;
using s16x4  = __attribute__((ext_vector_type(4))) short;
using s16x8  = __attribute__((ext_vector_type(8))) short;
using u32x4  = __attribute__((ext_vector_type(4))) unsigned;

#define DI __device__ __forceinline__

constexpr int HID  = 2048;
constexpr int NH   = 16;
constexpr int HD   = 128;
constexpr int TT   = 4096;   // total tokens
constexpr int SEQ  = 2048;
constexpr int NQKV = 3 * HID; // 6144
constexpr float SCL = 0.08838834764831845f * 1.4426950408889634f; // scale*log2e

DI short f2bf(float f) {
  unsigned u = __builtin_bit_cast(unsigned, f);
  unsigned r = (u + 0x7fffu + ((u >> 16) & 1u)) >> 16;
  return (short)r;
}
DI float bf2f(short s) {
  unsigned u = ((unsigned)(unsigned short)s) << 16;
  return __builtin_bit_cast(float, u);
}
DI unsigned cvtpk(float lo, float hi) {
  unsigned r;
  asm("v_cvt_pk_bf16_f32 %0, %1, %2" : "=v"(r) : "v"(lo), "v"(hi));
  return r;
}

// ---------------- merged prep: hidden conv + wqkv^T + wo^T (one launch) -----
struct alignas(8) S4h { short a, b, c, d; };

__global__ void prep(const float* __restrict__ hidden, short* __restrict__ Abf,
                     const float* __restrict__ wqkv, short* __restrict__ Wqkvt,
                     const float* __restrict__ wo, short* __restrict__ Wot) {
  __shared__ float t[64][65];
  const int bid = blockIdx.x;
  const int tid = threadIdx.x;
  if (bid < 8192) {                      // f32 -> bf16 convert of hidden
    int gid = bid * 256 + tid;
    float4 v = ((const float4*)hidden)[gid];
    S4h o{f2bf(v.x), f2bf(v.y), f2bf(v.z), f2bf(v.w)};
    ((S4h*)Abf)[gid] = o;
    return;
  }
  const float* in;
  short* out;
  int ldin, R, bx, by;
  if (bid < 8192 + 3072) {               // wqkv (2048 x 6144) -> (6144 x 2048)
    int idx = bid - 8192;
    in = wqkv; out = Wqkvt; ldin = NQKV; R = HID;
    bx = idx % 96; by = idx / 96;
  } else {                               // wo (2048 x 2048) -> (2048 x 2048)
    int idx = bid - 8192 - 3072;
    in = wo; out = Wot; ldin = HID; R = HID;
    bx = idx % 32; by = idx / 32;
  }
#pragma unroll
  for (int i = 0; i < 4; i++) {
    int idx = i * 256 + tid;
    int r = idx >> 4, c4 = idx & 15;
    size_t gi = (size_t)(by * 64 + r) * ldin + bx * 64 + c4 * 4;
    float4 v = *(const float4*)(in + gi);
    t[r][c4 * 4] = v.x; t[r][c4 * 4 + 1] = v.y;
    t[r][c4 * 4 + 2] = v.z; t[r][c4 * 4 + 3] = v.w;
  }
  __syncthreads();
#pragma unroll
  for (int i = 0; i < 4; i++) {
    int idx = i * 256 + tid;
    int r = idx >> 4, c4 = idx & 15;
    s16x4 o;
#pragma unroll
    for (int j = 0; j < 4; j++) o[j] = f2bf(t[c4 * 4 + j][r]);
    *(s16x4*)(out + (size_t)(bx * 64 + r) * R + by * 64 + c4 * 4) = o;
  }
}

// ---------------- post: Vt transpose (token bit-perm) + kc/vc cache scatter --
// blocks 0..2047: Vrow -> Vt transpose; dest col c holds source token
//   t(c) = (c>>5)*32 + ((c>>2)&1)*16 + ((c>>3)&3)*4 + (c&3)
// blocks 2048..6143: token-row copy Kb->kc, Vrow->vc (bf16 -> f32, slots scatter)
__global__ void post(const short* __restrict__ Kb, const short* __restrict__ Vrow,
                     short* __restrict__ Vt, const int* __restrict__ slots,
                     float* __restrict__ kc, float* __restrict__ vc) {
  __shared__ float t[64][65];
  const int bid = blockIdx.x;
  const int tid = threadIdx.x;
  if (bid < 2048) {
    int bx = bid & 31, by = bid >> 5;    // bx: HID/64, by: TT/64
#pragma unroll
    for (int i = 0; i < 4; i++) {
      int idx = i * 256 + tid;
      int r = idx >> 4, c4 = idx & 15;
      size_t gi = (size_t)(by * 64 + r) * HID + bx * 64 + c4 * 4;
      s16x4 v = *(const s16x4*)(Vrow + gi);
#pragma unroll
      for (int j = 0; j < 4; j++) t[r][c4 * 4 + j] = bf2f(v[j]);
    }
    __syncthreads();
#pragma unroll
    for (int i = 0; i < 4; i++) {
      int idx = i * 256 + tid;
      int r = idx >> 4, c4 = idx & 15;
      s16x4 o;
#pragma unroll
      for (int j = 0; j < 4; j++) {
        int c = c4 * 4 + j;
        int cs = (c >> 5) * 32 + ((c >> 2) & 1) * 16 + ((c >> 3) & 3) * 4 + (c & 3);
        o[j] = f2bf(t[cs][r]);
      }
      *(s16x4*)(Vt + (size_t)(bx * 64 + r) * TT + by * 64 + c4 * 4) = o;
    }
    return;
  }
  const int tok = bid - 2048;            // 0..4095
  const int slot = slots[tok];
  const short* kr = Kb + (size_t)tok * HID;
  const short* vr = Vrow + (size_t)tok * HID;
  float* kco = kc + (size_t)slot * HID;
  float* vco = vc + (size_t)slot * HID;
  const int i = tid * 8;
  s16x8 k8 = *(const s16x8*)(kr + i);
  s16x8 v8 = *(const s16x8*)(vr + i);
  *(float4*)(kco + i)     = {bf2f(k8[0]), bf2f(k8[1]), bf2f(k8[2]), bf2f(k8[3])};
  *(float4*)(kco + i + 4) = {bf2f(k8[4]), bf2f(k8[5]), bf2f(k8[6]), bf2f(k8[7])};
  *(float4*)(vco + i)     = {bf2f(v8[0]), bf2f(v8[1]), bf2f(v8[2]), bf2f(v8[3])};
  *(float4*)(vco + i + 4) = {bf2f(v8[4]), bf2f(v8[5]), bf2f(v8[6]), bf2f(v8[7])};
}

#define GLDS(src, dst)                                                     \
  __builtin_amdgcn_global_load_lds(                                        \
      (const __attribute__((address_space(1))) void*)(src),                \
      (__attribute__((address_space(3))) void*)(dst), 16, 0, 0)

// ---------------- bf16 MFMA GEMM, B transposed (N x K), 128x128 tile ----------
// Wave cols remapped to {0,32,64,96}+wc*16 so (d, d+64) pairs are lane-local.
// EPI=0: plain f32 out. EPI=1: fused bias+RoPE epilogue writing ONLY the bf16
// tensors (Qb rope'd+pre-scaled, Kb rope'd, Vrow); kc/vc moved to post kernel.
template <int EPI>
__global__ __launch_bounds__(256, 2) void gemm_bt(
    const short* __restrict__ A, const short* __restrict__ Bt,
    const float* __restrict__ bias, float* __restrict__ Cout,
    const float* __restrict__ cs, const float* __restrict__ sn,
    short* __restrict__ Qb, short* __restrict__ Kb, short* __restrict__ Vrow,
    int M, int N, int K) {
  __shared__ alignas(16) short Al[128 * 64];
  __shared__ alignas(16) short Bl[128 * 64];
  const int tid = threadIdx.x;
  const int wid = tid >> 6, lane = tid & 63;
  const int wr = wid >> 1, wc = wid & 1;
  const int l15 = lane & 15, lg = lane >> 4;
  // XCD-aware swizzle (grid counts are multiples of 8)
  const int gx = gridDim.x;
  const int id = blockIdx.y * gx + blockIdx.x;
  const int nwg = gx * gridDim.y;
  const int swz = (id & 7) * (nwg >> 3) + (id >> 3);
  const int row0 = (swz / gx) * 128, col0 = (swz % gx) * 128;
  const int lr8 = lane >> 3, l7 = lane & 7;

  f32x4 acc[4][4];
#pragma unroll
  for (int i = 0; i < 4; i++)
#pragma unroll
    for (int j = 0; j < 4; j++) acc[i][j] = {0.f, 0.f, 0.f, 0.f};

  for (int kt = 0; kt < K; kt += 64) {
#pragma unroll
    for (int c = 0; c < 4; c++) {
      int chunk = c * 4 + wid;             // 0..15 (1KB chunks)
      int r = chunk * 8 + lr8;             // LDS row 0..127
      int ke = (l7 * 8) ^ ((r & 7) * 8);   // element offset within 64-wide row
      GLDS(A + (size_t)(row0 + r) * K + kt + ke, Al + chunk * 512);
      GLDS(Bt + (size_t)(col0 + r) * K + kt + ke, Bl + chunk * 512);
    }
    __syncthreads();
#pragma unroll
    for (int kk = 0; kk < 2; kk++) {
      frag16 af[4], bfv[4];
#pragma unroll
      for (int ai = 0; ai < 4; ai++) {
        int r = wr * 64 + ai * 16 + l15;
        int k0 = kk * 32 + lg * 8;
        af[ai] = *(const frag16*)(Al + r * 64 + (k0 ^ ((r & 7) * 8)));
      }
#pragma unroll
      for (int bj = 0; bj < 4; bj++) {
        int r = wc * 16 + (bj & 1) * 32 + ((bj >> 1) << 6) + l15;
        int k0 = kk * 32 + lg * 8;
        bfv[bj] = *(const frag16*)(Bl + r * 64 + (k0 ^ ((r & 7) * 8)));
      }
#pragma unroll
      for (int ai = 0; ai < 4; ai++)
#pragma unroll
        for (int bj = 0; bj < 4; bj++)
          acc[ai][bj] = __builtin_amdgcn_mfma_f32_16x16x32_bf16(
              af[ai], bfv[bj], acc[ai][bj], 0, 0, 0);
    }
    __syncthreads();
  }

  if (EPI == 0) {
#pragma unroll
    for (int ai = 0; ai < 4; ai++) {
#pragma unroll
      for (int bj = 0; bj < 4; bj++) {
        int row = row0 + wr * 64 + ai * 16 + lg * 4;
        int col = col0 + wc * 16 + (bj & 1) * 32 + ((bj >> 1) << 6) + l15;
#pragma unroll
        for (int r = 0; r < 4; r++)
          Cout[(size_t)(row + r) * N + col] = acc[ai][bj][r];
      }
    }
  } else {
    const int sec = col0 >> 11;            // 0=Q 1=K 2=V (uniform per block)
    const int h = (col0 & 2047) >> 7;
#pragma unroll
    for (int ai = 0; ai < 4; ai++) {
#pragma unroll
      for (int bj = 0; bj < 2; bj++) {
        const int d1 = wc * 16 + bj * 32 + l15;   // 0..63
        const float b1 = bias[col0 + d1];
        const float b2 = bias[col0 + d1 + 64];
        const int base = h * 128 + d1;
#pragma unroll
        for (int r = 0; r < 4; r++) {
          const int tok = row0 + wr * 64 + ai * 16 + lg * 4 + r;
          float v1 = acc[ai][bj][r] + b1;
          float v2 = acc[ai][bj + 2][r] + b2;
          if (sec == 0) {
            float c = cs[tok * 64 + d1], s = sn[tok * 64 + d1];
            Qb[(size_t)tok * HID + base]      = f2bf((v1 * c - v2 * s) * SCL);
            Qb[(size_t)tok * HID + base + 64] = f2bf((v2 * c + v1 * s) * SCL);
          } else if (sec == 1) {
            float c = cs[tok * 64 + d1], s = sn[tok * 64 + d1];
            Kb[(size_t)tok * HID + base]      = f2bf(v1 * c - v2 * s);
            Kb[(size_t)tok * HID + base + 64] = f2bf(v2 * c + v1 * s);
          } else {
            Vrow[(size_t)tok * HID + base]      = f2bf(v1);
            Vrow[(size_t)tok * HID + base + 64] = f2bf(v2);
          }
        }
      }
    }
  }
}

// ---------------- causal flash attention v6: register-direct P ----------------
// Merged strip pairs (H=31-p, L=p share staged K/V prefix). Swapped QK^T puts
// P's q-row on l15 = exactly the PV A-operand's m=l15; lane's 16 in-register
// values fill A-slots k=lg*8+j / 32+lg*8+j under the token bit-perm baked
// into Vt -> P never touches LDS (8 cvt_pk -> two frag16).
__global__ __launch_bounds__(256, 2) void flash_attn6(
    const short* __restrict__ Qb, const short* __restrict__ Kb,
    const short* __restrict__ Vt, short* __restrict__ attn) {
  __shared__ alignas(16) short Klds[2][64 * 128];
  __shared__ alignas(16) short Vlds[2][128 * 64];

  const int tid = threadIdx.x;
  const int w = tid >> 6, lane = tid & 63;
  const int l15 = lane & 15, lg = lane >> 4;
  const int bid = blockIdx.x;
  const int p = bid >> 5;                  // 0..15: pair (31-p, p)
  const int bh = bid & 31;
  const int b = bh >> 4, h = bh & 15;

  frag16 ones;
#pragma unroll
  for (int j = 0; j < 8; j++) ones[j] = (short)0x3F80;

  auto stage = [&](int kv0, int buf) {
#pragma unroll
    for (int ci = 0; ci < 4; ci++) {
      int cc = w * 4 + ci;                 // 0..15
      int krow = cc * 4 + (lane >> 4);
      int kss = (lane & 15) ^ (krow & 15);
      GLDS(Kb + (size_t)(b * SEQ + kv0 + krow) * HID + h * HD + kss * 8,
           Klds[buf] + cc * 512);
      int vd = cc * 8 + (lane >> 3);
      int vss = (lane & 7) ^ (vd & 7);
      GLDS(Vt + (size_t)(h * HD + vd) * TT + b * SEQ + kv0 + vss * 8,
           Vlds[buf] + cc * 512);
    }
  };

  const int qrowH = (31 - p) * 64 + w * 16;
  const int qrowL = p * 64 + w * 16;
  const int ntH = 32 - p;                  // tiles for heavy strip

  frag16 qfH[4], qfL[4];
  {
    const short* qpH = Qb + (size_t)(b * SEQ + qrowH + l15) * HID + h * HD + lg * 8;
    const short* qpL = Qb + (size_t)(b * SEQ + qrowL + l15) * HID + h * HD + lg * 8;
#pragma unroll
    for (int ds = 0; ds < 4; ds++) {
      qfH[ds] = *(const frag16*)(qpH + ds * 32);
      qfL[ds] = *(const frag16*)(qpL + ds * 32);
    }
  }
  f32x4 oH[8], oL[8];
#pragma unroll
  for (int j = 0; j < 8; j++) { oH[j] = {0.f, 0.f, 0.f, 0.f}; oL[j] = {0.f, 0.f, 0.f, 0.f}; }
  f32x4 laH = {0.f, 0.f, 0.f, 0.f}, laL = {0.f, 0.f, 0.f, 0.f};
  float mrH = -1e30f, mrL = -1e30f;

  auto proc = [&](const frag16 (&qf)[4], f32x4 (&o)[8], f32x4& la, float& mr,
                  bool diag, const short* Kl, const short* Vl) {
    f32x4 sa[4];
#pragma unroll
    for (int f = 0; f < 4; f++) sa[f] = {0.f, 0.f, 0.f, 0.f};
    __builtin_amdgcn_s_setprio(1);
#pragma unroll
    for (int ds = 0; ds < 4; ds++) {
      int phys = (ds * 4 + lg) ^ l15;
#pragma unroll
      for (int f = 0; f < 4; f++) {
        frag16 kf = *(const frag16*)(Kl + (f * 16 + l15) * 128 + phys * 8);
        sa[f] = __builtin_amdgcn_mfma_f32_16x16x32_bf16(kf, qf[ds], sa[f], 0, 0, 0);
      }
    }
    __builtin_amdgcn_s_setprio(0);
    if (diag) {
      int ql = 16 * w + l15;
#pragma unroll
      for (int f = 0; f < 4; f++)
#pragma unroll
        for (int r = 0; r < 4; r++)
          if (f * 16 + lg * 4 + r > ql) sa[f][r] = -1e30f;
    }
    float pm = sa[0][0];
#pragma unroll
    for (int f = 0; f < 4; f++)
#pragma unroll
      for (int r = 0; r < 4; r++) pm = fmaxf(pm, sa[f][r]);
    pm = fmaxf(pm, __shfl_xor(pm, 16));
    pm = fmaxf(pm, __shfl_xor(pm, 32));
    if (__any(pm > mr + 8.f)) {
      float mn = fmaxf(mr, pm);
      float frl = exp2f(mr - mn);
      mr = mn;
      float fr4[4];
#pragma unroll
      for (int r = 0; r < 4; r++)
        fr4[r] = __shfl(frl, lg * 16 + lg * 4 + r);
#pragma unroll
      for (int r = 0; r < 4; r++) {
        la[r] *= fr4[r];
#pragma unroll
        for (int j = 0; j < 8; j++) o[j][r] *= fr4[r];
      }
    }
    float pe[4][4];
#pragma unroll
    for (int f = 0; f < 4; f++)
#pragma unroll
      for (int r = 0; r < 4; r++) pe[f][r] = exp2f(sa[f][r] - mr);
    // register-direct P: pf0 shorts j = pe[j>>2][j&3], pf1 = pe[2+(j>>2)][j&3]
    u32x4 w0, w1;
    w0[0] = cvtpk(pe[0][0], pe[0][1]); w0[1] = cvtpk(pe[0][2], pe[0][3]);
    w0[2] = cvtpk(pe[1][0], pe[1][1]); w0[3] = cvtpk(pe[1][2], pe[1][3]);
    w1[0] = cvtpk(pe[2][0], pe[2][1]); w1[1] = cvtpk(pe[2][2], pe[2][3]);
    w1[2] = cvtpk(pe[3][0], pe[3][1]); w1[3] = cvtpk(pe[3][2], pe[3][3]);
    frag16 pf0 = __builtin_bit_cast(frag16, w0);
    frag16 pf1 = __builtin_bit_cast(frag16, w1);
    __builtin_amdgcn_s_setprio(1);
    la = __builtin_amdgcn_mfma_f32_16x16x32_bf16(pf0, ones, la, 0, 0, 0);
    la = __builtin_amdgcn_mfma_f32_16x16x32_bf16(pf1, ones, la, 0, 0, 0);
#pragma unroll
    for (int j = 0; j < 8; j++) {
      int d = j * 16 + l15;
      int p0 = lg ^ (d & 7);
      int p1 = (4 + lg) ^ (d & 7);
      frag16 vf0 = *(const frag16*)(Vl + d * 64 + p0 * 8);
      frag16 vf1 = *(const frag16*)(Vl + d * 64 + p1 * 8);
      o[j] = __builtin_amdgcn_mfma_f32_16x16x32_bf16(pf0, vf0, o[j], 0, 0, 0);
      o[j] = __builtin_amdgcn_mfma_f32_16x16x32_bf16(pf1, vf1, o[j], 0, 0, 0);
    }
    __builtin_amdgcn_s_setprio(0);
  };

  stage(0, 0);
  __syncthreads();

  int cur = 0;
  for (int t = 0; t < ntH; t++) {
    if (t + 1 < ntH) stage((t + 1) * 64, cur ^ 1);
    const short* Kl = &Klds[cur][0];
    const short* Vl = &Vlds[cur][0];
    proc(qfH, oH, laH, mrH, t == ntH - 1, Kl, Vl);
    if (t <= p) proc(qfL, oL, laL, mrL, t == p, Kl, Vl);
    __syncthreads();
    cur ^= 1;
  }

  {
    float inv[4];
#pragma unroll
    for (int r = 0; r < 4; r++) inv[r] = 1.f / laH[r];
    short* op = attn + (size_t)(b * SEQ + qrowH + lg * 4) * HID + h * HD + l15;
#pragma unroll
    for (int j = 0; j < 8; j++)
#pragma unroll
      for (int r = 0; r < 4; r++)
        op[(size_t)r * HID + j * 16] = f2bf(oH[j][r] * inv[r]);
  }
  {
    float inv[4];
#pragma unroll
    for (int r = 0; r < 4; r++) inv[r] = 1.f / laL[r];
    short* op = attn + (size_t)(b * SEQ + qrowL + lg * 4) * HID + h * HD + l15;
#pragma unroll
    for (int j = 0; j < 8; j++)
#pragma unroll
      for (int r = 0; r < 4; r++)
        op[(size_t)r * HID + j * 16] = f2bf(oL[j][r] * inv[r]);
  }
}

// ---------------- launcher ----------------
extern "C" void kernel_launch(void* const* d_in, const int* in_sizes, int n_in,
                              void* d_out, int out_size, void* d_ws, size_t ws_size,
                              hipStream_t stream) {
  const float* hidden = (const float*)d_in[0];
  const float* cosb   = (const float*)d_in[1];
  const float* sinb   = (const float*)d_in[2];
  const float* wqkv   = (const float*)d_in[3];
  const float* bqkv   = (const float*)d_in[4];
  const float* wo     = (const float*)d_in[5];
  const int*   slots  = (const int*)d_in[9];

  float* out = (float*)d_out;
  float* kc  = out + (size_t)TT * HID;
  float* vc  = kc + (size_t)TT * HID;

  short* ws    = (short*)d_ws;
  short* Abf   = ws;                       // 8,388,608 shorts (reused as attnb)
  short* Wqkvt = Abf + 8388608;            // 12,582,912
  short* Wot   = Wqkvt + 12582912;         // 4,194,304
  short* Qb    = Wot + 4194304;            // 8,388,608
  short* Kb    = Qb + 8388608;             // 8,388,608
  short* Vrow  = Kb + 8388608;             // 8,388,608
  short* Vt    = Vrow + 8388608;           // 8,388,608
  short* attnb = Abf;                      // reuse (A dead after GEMM1)

  prep<<<8192 + 3072 + 1024, 256, 0, stream>>>(hidden, Abf, wqkv, Wqkvt, wo, Wot);
  gemm_bt<1><<<dim3(48, 32), 256, 0, stream>>>(
      Abf, Wqkvt, bqkv, nullptr, cosb, sinb, Qb, Kb, Vrow, TT, NQKV, HID);
  post<<<2048 + 4096, 256, 0, stream>>>(Kb, Vrow, Vt, slots, kc, vc);
  flash_attn6<<<512, 256, 0, stream>>>(Qb, Kb, Vt, attnb);
  gemm_bt<0><<<dim3(16, 32), 256, 0, stream>>>(
      attnb, Wot, nullptr, out, nullptr, nullptr, nullptr, nullptr, nullptr,
      TT, HID, HID);
}